// Round 1
// baseline (193.463 us; speedup 1.0000x reference)
//
#include <hip/hip_runtime.h>

// ConstrainDotAttention: B=4,H=12,S=2048,Dk=Dv=64, fp32 in/out.
// out = (mask * softmax(QK^T/8)) @ V, mask per-key.
// R4: 32x32x16 MFMA pipeline. S^T = K*(Qc)^T via 32x32 tiles; exp2 results
//     packed with cvt + v_permlane32_swap (T12) into FULL K=16 32x32 B-frags
//     so PV runs at full 32x32 rate (was half-rate 16x16x16).
//     XOR-swizzled LDS (T2) kills the 9.4M bank-conflict cycles.
//     Double-buffered LDS -> ONE barrier per tile, prefetch distance 2.

typedef _Float16 f16x8 __attribute__((ext_vector_type(8)));
typedef _Float16 f16x2 __attribute__((ext_vector_type(2)));
typedef float    f32x16 __attribute__((ext_vector_type(16)));
typedef int      i32x2 __attribute__((ext_vector_type(2)));
typedef int      i32x4 __attribute__((ext_vector_type(4)));

#define SEQ  2048
#define DIM  64
#define KT   64
#define NIT  (SEQ / KT)

__device__ __forceinline__ f16x8 cvt8(float4 a, float4 b) {
    return (f16x8){(_Float16)a.x,(_Float16)a.y,(_Float16)a.z,(_Float16)a.w,
                   (_Float16)b.x,(_Float16)b.y,(_Float16)b.z,(_Float16)b.w};
}
__device__ __forceinline__ f16x8 cvt8s(float4 a, float4 b, float s) {
    return (f16x8){(_Float16)(a.x*s),(_Float16)(a.y*s),(_Float16)(a.z*s),(_Float16)(a.w*s),
                   (_Float16)(b.x*s),(_Float16)(b.y*s),(_Float16)(b.z*s),(_Float16)(b.w*s)};
}
__device__ __forceinline__ int pk2(float a, float b) {   // RNE pack, elem0 = a (low half)
    f16x2 t = {(_Float16)a, (_Float16)b};
    return __builtin_bit_cast(int, t);
}
// XOR-swizzle: rows are 64 halfs (128B = 8 x 16B blocks). Swizzle 16B-block
// index with row&7 -> every 8-lane b128 phase hits 8 distinct block slots.
__device__ __forceinline__ int swz(int row, int colh) {
    return (row << 6) + (colh ^ ((row & 7) << 3));
}
// v_permlane32_swap_b32: r[0] = {a.lo32lanes, b.lo32lanes}, r[1] = {a.hi, b.hi}
__device__ __forceinline__ i32x2 plswap(int a, int b) {
#if __has_builtin(__builtin_amdgcn_permlane32_swap)
    return __builtin_amdgcn_permlane32_swap(a, b, false, false);
#else
    int ax = __shfl_xor(a, 32);
    int bx = __shfl_xor(b, 32);
    i32x2 r;
    r[0] = (threadIdx.x & 32) ? bx : a;
    r[1] = (threadIdx.x & 32) ? b  : ax;
    return r;
#endif
}

__global__ __launch_bounds__(256, 3)
void fa_kernel(const float* __restrict__ Q, const float* __restrict__ K,
               const float* __restrict__ V, const float* __restrict__ Mask,
               float* __restrict__ Out)
{
    __shared__ __align__(16) _Float16 Kld[2][KT * DIM];   // [key][d], swizzled
    __shared__ __align__(16) _Float16 Vt [2][DIM * KT];   // [d][key], mask-folded, swizzled

    const int bx    = blockIdx.x;
    const int head  = bx % 48;               // same head -> same XCD (48%8==0)
    const int qtile = bx / 48;
    const int tid   = threadIdx.x;
    const int wave  = tid >> 6;
    const int lane  = tid & 63;
    const int cl    = lane & 31;             // qrow / m-row lane index
    const int hl    = lane >> 5;             // half-wave select

    const size_t hoff = (size_t)head * SEQ * DIM;
    const float* Qh = Q + hoff;
    const float* Kh = K + hoff;
    const float* Vh = V + hoff;
    const float* Mh = Mask + (size_t)head * SEQ;
    float* Oh = Out + hoff;

    const int qbase = qtile * 128 + wave * 32;
    const float c = 0.18033688011112042f;    // log2(e)/sqrt(64), folded into Q

    // ---- Q B-fragments, pre-scaled. B[k=d][n=qrow]: n=cl, k = kk*16 + hl*8 + j
    f16x8 qf[4];
    {
        const float* qrow = Qh + (size_t)(qbase + cl) * DIM;
        #pragma unroll
        for (int kk = 0; kk < 4; ++kk) {
            const float4* p4 = (const float4*)(qrow + kk * 16 + hl * 8);
            qf[kk] = cvt8s(p4[0], p4[1], c);
        }
    }

    // O^T accumulators: o[dt], C-layout col=qrow(cl), row=d=(reg&3)+8*(reg>>2)+4*hl+32*dt
    f32x16 o[2];
    #pragma unroll
    for (int dt = 0; dt < 2; ++dt)
        #pragma unroll
        for (int i = 0; i < 16; ++i) o[dt][i] = 0.f;
    float lsum = 0.f;                        // per-lane, qrow = cl (both halves)

    // staging assignments
    const int skey = tid >> 2;               // K: key 0..63
    const int sdb  = (tid & 3) * 16;         // K: 16 d's
    const int vk0  = (tid & 31) * 2;         // V: key pair base
    const int vdb  = (tid >> 5) * 8;         // V: 8 d's

    // ---- prefetch registers (distance 2)
    float4 kr0, kr1, kr2, kr3, va0, va1, vb0, vb1;
    float mk0, mk1;
    auto load_tile = [&](int kbase) {
        const float4* kg = (const float4*)(Kh + (size_t)(kbase + skey) * DIM + sdb);
        kr0 = kg[0]; kr1 = kg[1]; kr2 = kg[2]; kr3 = kg[3];
        const float4* vg0 = (const float4*)(Vh + (size_t)(kbase + vk0) * DIM + vdb);
        const float4* vg1 = (const float4*)(Vh + (size_t)(kbase + vk0 + 1) * DIM + vdb);
        va0 = vg0[0]; va1 = vg0[1];
        vb0 = vg1[0]; vb1 = vg1[1];
        mk0 = Mh[kbase + vk0]; mk1 = Mh[kbase + vk0 + 1];
    };
    auto stage = [&](int b) {
        *(f16x8*)&Kld[b][swz(skey, sdb)]     = cvt8(kr0, kr1);
        *(f16x8*)&Kld[b][swz(skey, sdb + 8)] = cvt8(kr2, kr3);
        float va[8] = {va0.x, va0.y, va0.z, va0.w, va1.x, va1.y, va1.z, va1.w};
        float vb[8] = {vb0.x, vb0.y, vb0.z, vb0.w, vb1.x, vb1.y, vb1.z, vb1.w};
        #pragma unroll
        for (int j = 0; j < 8; ++j) {
            f16x2 w = {(_Float16)(va[j] * mk0), (_Float16)(vb[j] * mk1)};
            *(f16x2*)&Vt[b][swz(vdb + j, vk0)] = w;
        }
    };

    // prologue: tile0 -> LDS[0]; tile1 -> regs
    load_tile(0);
    stage(0);
    load_tile(KT);
    __syncthreads();

    int buf = 0;
    for (int kbi = 0; kbi < NIT; ++kbi) {
        // stage tile kbi+1 (in regs) into the other buffer; its last readers
        // finished before the barrier ending iter kbi-1.
        if (kbi + 1 < NIT) stage(buf ^ 1);
        if (kbi + 2 < NIT) load_tile((kbi + 2) * KT);

        #pragma unroll
        for (int kt2 = 0; kt2 < 2; ++kt2) {
            // ---- S^T = K (Qc)^T - 8 on a 32key x 32qrow tile
            // A = K frag: A[m=key][k=d]: m = kt2*32+cl, k = kk*16 + hl*8 + j
            f16x8 kf[4];
            #pragma unroll
            for (int kk = 0; kk < 4; ++kk)
                kf[kk] = *(const f16x8*)&Kld[buf][swz(kt2 * 32 + cl, kk * 16 + hl * 8)];

            f32x16 acc;
            #pragma unroll
            for (int i = 0; i < 16; ++i) acc[i] = -8.f;    // exp2-shift via C-init
            #pragma unroll
            for (int kk = 0; kk < 4; ++kk)
                acc = __builtin_amdgcn_mfma_f32_32x32x16_f16(kf[kk], qf[kk], acc, 0, 0, 0);

            // lane holds keys {0-3,8-11,16-19,24-27}+4*hl (col = qrow = cl)
            float p[16];
            #pragma unroll
            for (int i = 0; i < 16; ++i) p[i] = __builtin_amdgcn_exp2f(acc[i]);
            {
                float s0 = (p[0] + p[1])  + (p[2] + p[3]);
                float s1 = (p[4] + p[5])  + (p[6] + p[7]);
                float s2 = (p[8] + p[9])  + (p[10] + p[11]);
                float s3 = (p[12] + p[13]) + (p[14] + p[15]);
                lsum += (s0 + s1) + (s2 + s3);
            }

            // ---- pack + permlane32_swap -> K=16 B-frags B[k=key][n=qrow]
            // chunk ch covers keys kt2*32 + ch*16 .. +15; lane needs k = hl*8+j.
            f16x8 pf[2];
            #pragma unroll
            for (int ch = 0; ch < 2; ++ch) {
                int x0 = pk2(p[8*ch + 0], p[8*ch + 1]);   // lo:(k0,k1)  hi:(k4,k5)
                int x1 = pk2(p[8*ch + 2], p[8*ch + 3]);   // lo:(k2,k3)  hi:(k6,k7)
                int y0 = pk2(p[8*ch + 4], p[8*ch + 5]);   // lo:(k8,k9)  hi:(k12,k13)
                int y1 = pk2(p[8*ch + 6], p[8*ch + 7]);   // lo:(k10,k11)hi:(k14,k15)
                i32x2 s0 = plswap(x0, y0);                // s0[0]=b0{01|89} s0[1]=b2{45|12,13}
                i32x2 s1 = plswap(x1, y1);                // s1[0]=b1{23|10,11} s1[1]=b3{67|14,15}
                i32x4 w; w[0] = s0[0]; w[1] = s1[0]; w[2] = s0[1]; w[3] = s1[1];
                pf[ch] = __builtin_bit_cast(f16x8, w);
            }

            // ---- O^T += V^T P, full-rate 32x32x16
            // A = V^T frag: A[m=d][k=key]: m = dt*32+cl, k = kt2*32+ch*16+hl*8+j
            #pragma unroll
            for (int dt = 0; dt < 2; ++dt) {
                #pragma unroll
                for (int ch = 0; ch < 2; ++ch) {
                    f16x8 vf = *(const f16x8*)&Vt[buf][swz(dt * 32 + cl,
                                                           kt2 * 32 + ch * 16 + hl * 8)];
                    o[dt] = __builtin_amdgcn_mfma_f32_32x32x16_f16(vf, pf[ch], o[dt], 0, 0, 0);
                }
            }
        }

        __syncthreads();                     // one barrier per tile (dbuf)
        buf ^= 1;
    }

    // ---- epilogue: l per qrow; lanes l and l+32 share qrow
    float l = lsum + __shfl_xor(lsum, 32);
    float inv = 1.0f / l;
    const size_t rowoff = (size_t)(qbase + cl) * DIM;
    #pragma unroll
    for (int dt = 0; dt < 2; ++dt) {
        #pragma unroll
        for (int g = 0; g < 4; ++g) {
            float4 v = {o[dt][4*g + 0] * inv, o[dt][4*g + 1] * inv,
                        o[dt][4*g + 2] * inv, o[dt][4*g + 3] * inv};
            *(float4*)&Oh[rowoff + dt * 32 + g * 8 + hl * 4] = v;
        }
    }
}

extern "C" void kernel_launch(void* const* d_in, const int* in_sizes, int n_in,
                              void* d_out, int out_size, void* d_ws, size_t ws_size,
                              hipStream_t stream) {
    const float* Q = (const float*)d_in[0];
    const float* K = (const float*)d_in[1];
    const float* V = (const float*)d_in[2];
    const float* M = (const float*)d_in[3];
    float* O = (float*)d_out;
    dim3 grid(768), block(256);
    hipLaunchKernelGGL(fa_kernel, grid, block, 0, stream, Q, K, V, M, O);
}